// Round 1
// baseline (703.322 us; speedup 1.0000x reference)
//
#include <hip/hip_runtime.h>
#include <math.h>

#define BB 8
#define SS 2048
#define DDIM 128
#define NTOK (BB * SS)   // 16384

__device__ __forceinline__ float gelu_exact(float v) {
    return 0.5f * v * (1.0f + erff(v * 0.70710678118654752f));
}

// ---------------------------------------------------------------------------
// Generic tiled GEMM: C[m*ldc+n] = epi( sum_k A[m*K+k] * W[n*K+k] + bias[n] )
// epi: if act==1 -> gelu; if scale -> *= scale[m]; if res -> += res[m*ldc+n]
// M % 64 == 0, N % 64 == 0, K % 32 == 0
// ---------------------------------------------------------------------------
__global__ __launch_bounds__(256) void gemm_kernel(
    const float* __restrict__ A, const float* __restrict__ W,
    const float* __restrict__ bias,
    const float* __restrict__ res,
    const float* __restrict__ scale,
    float* __restrict__ C,
    int M, int N, int K, int ldc, int act)
{
    __shared__ float As[32][65];   // [k][m], +1 pad
    __shared__ float Ws[32][65];   // [k][n]
    const int tid = threadIdx.x;
    const int tx = tid % 16, ty = tid / 16;
    const int m0 = blockIdx.x * 64, n0 = blockIdx.y * 64;

    float acc[4][4] = {};

    for (int k0 = 0; k0 < K; k0 += 32) {
        for (int i = tid; i < 64 * 32; i += 256) {
            int r = i / 32, c = i % 32;
            As[c][r] = A[(size_t)(m0 + r) * K + k0 + c];
            Ws[c][r] = W[(size_t)(n0 + r) * K + k0 + c];
        }
        __syncthreads();
        for (int kk = 0; kk < 32; ++kk) {
            float a[4], w[4];
            #pragma unroll
            for (int i = 0; i < 4; ++i) a[i] = As[kk][ty * 4 + i];
            #pragma unroll
            for (int j = 0; j < 4; ++j) w[j] = Ws[kk][tx * 4 + j];
            #pragma unroll
            for (int i = 0; i < 4; ++i)
                #pragma unroll
                for (int j = 0; j < 4; ++j)
                    acc[i][j] = fmaf(a[i], w[j], acc[i][j]);
        }
        __syncthreads();
    }

    #pragma unroll
    for (int i = 0; i < 4; ++i) {
        int m = m0 + ty * 4 + i;
        float sc = (scale != nullptr) ? scale[m] : 1.0f;
        #pragma unroll
        for (int j = 0; j < 4; ++j) {
            int n = n0 + tx * 4 + j;
            float v = acc[i][j] + bias[n];
            if (act == 1) v = gelu_exact(v);
            v *= sc;
            if (res != nullptr) v += res[(size_t)m * ldc + n];
            C[(size_t)m * ldc + n] = v;
        }
    }
}

// ---------------------------------------------------------------------------
// LayerNorm over rows of 128 (in-place), eps = 1e-5
// ---------------------------------------------------------------------------
__global__ __launch_bounds__(128) void ln_kernel(
    float* __restrict__ x, const float* __restrict__ g, const float* __restrict__ b)
{
    const int row = blockIdx.x, tid = threadIdx.x;
    __shared__ float red[128];
    float v = x[(size_t)row * 128 + tid];
    red[tid] = v; __syncthreads();
    for (int s = 64; s > 0; s >>= 1) { if (tid < s) red[tid] += red[tid + s]; __syncthreads(); }
    float mu = red[0] * (1.0f / 128.0f);
    __syncthreads();
    float dv = v - mu;
    red[tid] = dv * dv; __syncthreads();
    for (int s = 64; s > 0; s >>= 1) { if (tid < s) red[tid] += red[tid + s]; __syncthreads(); }
    float var = red[0] * (1.0f / 128.0f);
    x[(size_t)row * 128 + tid] = dv * rsqrtf(var + 1e-5f) * g[tid] + b[tid];
}

// ---------------------------------------------------------------------------
// Cosine normalize rows of 128: out = in / max(||in||, 1e-8)
// ---------------------------------------------------------------------------
__global__ __launch_bounds__(128) void cosnorm_kernel(
    const float* __restrict__ in, float* __restrict__ out)
{
    const int row = blockIdx.x, tid = threadIdx.x;
    __shared__ float red[128];
    float v = in[(size_t)row * 128 + tid];
    red[tid] = v * v; __syncthreads();
    for (int s = 64; s > 0; s >>= 1) { if (tid < s) red[tid] += red[tid + s]; __syncthreads(); }
    float n = fmaxf(sqrtf(red[0]), 1e-8f);
    out[(size_t)row * 128 + tid] = v / n;
}

// ---------------------------------------------------------------------------
// Windowed causal attention. qkv: (NTOK, 384) = [q|k|v], heads of 16.
// Block = (window w in [0,256), head h in [0,8)), 64 threads; thread = query row.
// out: (NTOK, 128) head-concat.
// ---------------------------------------------------------------------------
__global__ __launch_bounds__(64) void win_attn_kernel(
    const float* __restrict__ qkv, float* __restrict__ out)
{
    const int w = blockIdx.x, h = blockIdx.y, l = threadIdx.x;
    __shared__ float Ks[64][16];
    __shared__ float Vs[64][16];
    const float* base = qkv + (size_t)(w * 64 + l) * 384 + h * 16;
    #pragma unroll
    for (int c4 = 0; c4 < 16; c4 += 4) {
        *(float4*)&Ks[l][c4] = *(const float4*)(base + 128 + c4);
        *(float4*)&Vs[l][c4] = *(const float4*)(base + 256 + c4);
    }
    float q[16];
    #pragma unroll
    for (int c = 0; c < 16; ++c) q[c] = base[c];
    __syncthreads();

    float m = -1e30f, ssum = 0.0f;
    float o[16] = {};
    for (int j = 0; j <= l; ++j) {
        float s = 0.0f;
        #pragma unroll
        for (int c = 0; c < 16; ++c) s = fmaf(q[c], Ks[j][c], s);
        s *= 0.25f;                       // 1/sqrt(16)
        float mnew = fmaxf(m, s);
        float corr = expf(m - mnew);      // first iter: exp(-huge) = 0
        float p = expf(s - mnew);
        ssum = ssum * corr + p;
        #pragma unroll
        for (int c = 0; c < 16; ++c) o[c] = o[c] * corr + p * Vs[j][c];
        m = mnew;
    }
    float inv = 1.0f / ssum;
    float* op = out + (size_t)(w * 64 + l) * 128 + h * 16;
    #pragma unroll
    for (int c = 0; c < 16; ++c) op[c] = o[c] * inv;
}

// ---------------------------------------------------------------------------
// M_b[d][e] = sum_j sn[b][j][d] * tn[b][j][e]   (A^T B per batch)
// grid (2,2,8), 256 threads, 64x64 tile.
// ---------------------------------------------------------------------------
__global__ __launch_bounds__(256) void atb_kernel(
    const float* __restrict__ sn, const float* __restrict__ tn, float* __restrict__ Mb)
{
    const int b = blockIdx.z;
    const int d0 = blockIdx.x * 64, e0 = blockIdx.y * 64;
    __shared__ float Ss[32][65];
    __shared__ float Ts[32][65];
    const int tid = threadIdx.x;
    const int tx = tid % 16, ty = tid / 16;
    const float* sb = sn + (size_t)b * SS * 128;
    const float* tb = tn + (size_t)b * SS * 128;
    float acc[4][4] = {};
    for (int j0 = 0; j0 < SS; j0 += 32) {
        for (int i = tid; i < 32 * 64; i += 256) {
            int r = i / 64, c = i % 64;
            Ss[r][c] = sb[(size_t)(j0 + r) * 128 + d0 + c];
            Ts[r][c] = tb[(size_t)(j0 + r) * 128 + e0 + c];
        }
        __syncthreads();
        for (int kk = 0; kk < 32; ++kk) {
            float a[4], w[4];
            #pragma unroll
            for (int i = 0; i < 4; ++i) a[i] = Ss[kk][ty * 4 + i];
            #pragma unroll
            for (int j = 0; j < 4; ++j) w[j] = Ts[kk][tx * 4 + j];
            #pragma unroll
            for (int i = 0; i < 4; ++i)
                #pragma unroll
                for (int j = 0; j < 4; ++j)
                    acc[i][j] = fmaf(a[i], w[j], acc[i][j]);
        }
        __syncthreads();
    }
    #pragma unroll
    for (int i = 0; i < 4; ++i)
        #pragma unroll
        for (int j = 0; j < 4; ++j)
            Mb[(size_t)b * 16384 + (size_t)(d0 + ty * 4 + i) * 128 + (e0 + tx * 4 + j)] = acc[i][j];
}

// ---------------------------------------------------------------------------
// sim[row] = (1/S) * sn_row^T M_b tn_row.  16 rows per block, 256 threads.
// ---------------------------------------------------------------------------
__global__ __launch_bounds__(256) void sim_kernel(
    const float* __restrict__ sn, const float* __restrict__ tn,
    const float* __restrict__ Mb, float* __restrict__ sim)
{
    const int row0 = blockIdx.x * 16;
    const int b = row0 / SS;              // 16 | 2048, no straddle
    __shared__ float sn_s[16][128];
    __shared__ float tn_s[16][128];
    __shared__ float red[16][128];
    const int tid = threadIdx.x;
    for (int i4 = tid; i4 < 512; i4 += 256) {
        int r = i4 / 32, c4 = (i4 % 32) * 4;
        *(float4*)&sn_s[r][c4] = *(const float4*)&sn[(size_t)(row0 + r) * 128 + c4];
        *(float4*)&tn_s[r][c4] = *(const float4*)&tn[(size_t)(row0 + r) * 128 + c4];
    }
    __syncthreads();
    const int e = tid % 128, half = tid / 128;
    float acc[8] = {};
    const float* Mp = Mb + (size_t)b * 16384;
    for (int d = 0; d < 128; ++d) {
        float mv = Mp[(size_t)d * 128 + e];
        #pragma unroll
        for (int r = 0; r < 8; ++r) acc[r] = fmaf(sn_s[half * 8 + r][d], mv, acc[r]);
    }
    #pragma unroll
    for (int r = 0; r < 8; ++r) red[half * 8 + r][e] = acc[r] * tn_s[half * 8 + r][e];
    __syncthreads();
    if (tid < 16) {
        float s = 0.0f;
        for (int e2 = 0; e2 < 128; ++e2) s += red[tid][e2];
        sim[row0 + tid] = s * (1.0f / (float)SS);
    }
}

// ---------------------------------------------------------------------------
// Interaction attention (seq over batch dim, len=8, heads=8, hd=16, no mask).
// qkvi: (NTOK, 384) with rows (b*S+s); q from se, k/v from te (precomputed).
// Block per s, 64 threads. Writes AO (NTOK, 128).
// ---------------------------------------------------------------------------
__global__ __launch_bounds__(64) void inter_attn_kernel(
    const float* __restrict__ qkvi, float* __restrict__ AO)
{
    const int s = blockIdx.x, tid = threadIdx.x;
    __shared__ float Q[8][128];
    __shared__ float Km[8][128];
    __shared__ float Vm[8][128];
    __shared__ float P[8][8][8];   // [h][i][j]
    for (int i4 = tid; i4 < 768; i4 += 64) {
        int mat = i4 / 256, rem = i4 % 256;
        int i = rem / 32, c4 = (rem % 32) * 4;
        float4 v = *(const float4*)(qkvi + (size_t)(i * SS + s) * 384 + mat * 128 + c4);
        float* dst = (mat == 0) ? &Q[i][c4] : (mat == 1) ? &Km[i][c4] : &Vm[i][c4];
        *(float4*)dst = v;
    }
    __syncthreads();
    for (int idx = tid; idx < 512; idx += 64) {
        int h = idx >> 6, i = (idx >> 3) & 7, j = idx & 7;
        float sum = 0.0f;
        #pragma unroll
        for (int c = 0; c < 16; ++c) sum = fmaf(Q[i][h * 16 + c], Km[j][h * 16 + c], sum);
        P[h][i][j] = sum * 0.25f;
    }
    __syncthreads();
    {   // softmax per (h,i): exactly 64 rows
        int h = tid >> 3, i = tid & 7;
        float m = -1e30f;
        #pragma unroll
        for (int j = 0; j < 8; ++j) m = fmaxf(m, P[h][i][j]);
        float pj[8], ssum = 0.0f;
        #pragma unroll
        for (int j = 0; j < 8; ++j) { pj[j] = expf(P[h][i][j] - m); ssum += pj[j]; }
        float inv = 1.0f / ssum;
        #pragma unroll
        for (int j = 0; j < 8; ++j) P[h][i][j] = pj[j] * inv;
    }
    __syncthreads();
    for (int o = tid; o < 1024; o += 64) {
        int i = o >> 7, c = o & 127, h = c >> 4;
        float sum = 0.0f;
        #pragma unroll
        for (int j = 0; j < 8; ++j) sum = fmaf(P[h][i][j], Vm[j][c], sum);
        AO[(size_t)(i * SS + s) * 128 + c] = sum;
    }
}

// ---------------------------------------------------------------------------
extern "C" void kernel_launch(void* const* d_in, const int* in_sizes, int n_in,
                              void* d_out, int out_size, void* d_ws, size_t ws_size,
                              hipStream_t stream)
{
    const float* x        = (const float*)d_in[0];
    const float* spatial  = (const float*)d_in[1];
    const float* temporal = (const float*)d_in[2];
    const float* lw_in_w  = (const float*)d_in[3];
    const float* lw_in_b  = (const float*)d_in[4];
    const float* lw_out_w = (const float*)d_in[5];
    const float* lw_out_b = (const float*)d_in[6];
    const float* spat_w   = (const float*)d_in[7];
    const float* spat_b   = (const float*)d_in[8];
    const float* temp_w   = (const float*)d_in[9];
    const float* temp_b   = (const float*)d_in[10];
    const float* int_in_w = (const float*)d_in[11];
    const float* int_in_b = (const float*)d_in[12];
    const float* int_out_w= (const float*)d_in[13];
    const float* int_out_b= (const float*)d_in[14];
    const float* ffn_w1   = (const float*)d_in[15];
    const float* ffn_b1   = (const float*)d_in[16];
    const float* ffn_w2   = (const float*)d_in[17];
    const float* ffn_b2   = (const float*)d_in[18];
    const float* ln1_g    = (const float*)d_in[19];
    const float* ln1_b    = (const float*)d_in[20];
    const float* ln2_g    = (const float*)d_in[21];
    const float* ln2_b    = (const float*)d_in[22];
    float* out = (float*)d_out;

    float* ws = (float*)d_ws;
    float* qkvbuf = ws;                     // 6,291,456 (qkv_win; later qkv_int)
    float* attnbuf = qkvbuf + 6291456;      // 2,097,152 (attn out; later AO)
    float* x1buf  = attnbuf + 2097152;      // 2,097,152 (t1/x1; later se)
    float* hbuf   = x1buf + 2097152;        // 8,388,608 (h; later te overlays)
    float* x2buf  = hbuf + 8388608;         // 2,097,152
    float* snbuf  = x2buf + 2097152;        // 2,097,152
    float* tnbuf  = snbuf + 2097152;        // 2,097,152
    float* Mbuf   = tnbuf + 2097152;        // 131,072
    float* simbuf = Mbuf + 131072;          // 16,384
    float* sebuf = x1buf;                   // alias (x1 dead after FFN2)
    float* tebuf = hbuf;                    // alias (h dead after FFN2)

    // --- 1. window QKV: (NTOK,384) = x @ lw_in_w^T + b ---
    gemm_kernel<<<dim3(NTOK / 64, 6), 256, 0, stream>>>(
        x, lw_in_w, lw_in_b, nullptr, nullptr, qkvbuf, NTOK, 384, 128, 384, 0);
    // --- 2. windowed causal attention ---
    win_attn_kernel<<<dim3(256, 8), 64, 0, stream>>>(qkvbuf, attnbuf);
    // --- 3. out proj + residual(x) ---
    gemm_kernel<<<dim3(NTOK / 64, 2), 256, 0, stream>>>(
        attnbuf, lw_out_w, lw_out_b, x, nullptr, x1buf, NTOK, 128, 128, 128, 0);
    // --- 4. LN1 (in place) ---
    ln_kernel<<<NTOK, 128, 0, stream>>>(x1buf, ln1_g, ln1_b);
    // --- 5. FFN1 + exact GELU ---
    gemm_kernel<<<dim3(NTOK / 64, 8), 256, 0, stream>>>(
        x1buf, ffn_w1, ffn_b1, nullptr, nullptr, hbuf, NTOK, 512, 128, 512, 1);
    // --- 6. FFN2 + residual(x1) ---
    gemm_kernel<<<dim3(NTOK / 64, 2), 256, 0, stream>>>(
        hbuf, ffn_w2, ffn_b2, x1buf, nullptr, x2buf, NTOK, 128, 512, 128, 0);
    // --- 7. LN2 (in place) ---
    ln_kernel<<<NTOK, 128, 0, stream>>>(x2buf, ln2_g, ln2_b);
    // --- 8/9. se, te projections ---
    gemm_kernel<<<dim3(NTOK / 64, 2), 256, 0, stream>>>(
        spatial, spat_w, spat_b, nullptr, nullptr, sebuf, NTOK, 128, 128, 128, 0);
    gemm_kernel<<<dim3(NTOK / 64, 2), 256, 0, stream>>>(
        temporal, temp_w, temp_b, nullptr, nullptr, tebuf, NTOK, 128, 128, 128, 0);
    // --- 10. cosine norms ---
    cosnorm_kernel<<<NTOK, 128, 0, stream>>>(sebuf, snbuf);
    cosnorm_kernel<<<NTOK, 128, 0, stream>>>(tebuf, tnbuf);
    // --- 11. M_b = sn^T tn per batch ---
    atb_kernel<<<dim3(2, 2, 8), 256, 0, stream>>>(snbuf, tnbuf, Mbuf);
    // --- 12. sim = (1/S) sn^T M tn per row ---
    sim_kernel<<<NTOK / 16, 256, 0, stream>>>(snbuf, tnbuf, Mbuf, simbuf);
    // --- 13. interaction QKV: q from se, k/v from te ---
    gemm_kernel<<<dim3(NTOK / 64, 2), 256, 0, stream>>>(
        sebuf, int_in_w, int_in_b, nullptr, nullptr, qkvbuf, NTOK, 128, 128, 384, 0);
    gemm_kernel<<<dim3(NTOK / 64, 4), 256, 0, stream>>>(
        tebuf, int_in_w + 128 * 128, int_in_b + 128, nullptr, nullptr,
        qkvbuf + 128, NTOK, 256, 128, 384, 0);
    // --- 14. interaction attention ---
    inter_attn_kernel<<<SS, 64, 0, stream>>>(qkvbuf, attnbuf);
    // --- 15. out proj * sim + x2 -> d_out ---
    gemm_kernel<<<dim3(NTOK / 64, 2), 256, 0, stream>>>(
        attnbuf, int_out_w, int_out_b, x2buf, simbuf, out, NTOK, 128, 128, 128, 0);
}

// Round 2
// 371.480 us; speedup vs baseline: 1.8933x; 1.8933x over previous
//
#include <hip/hip_runtime.h>
#include <math.h>

#define BB 8
#define SS 2048
#define DDIM 128
#define NTOK (BB * SS)   // 16384
#define ATB_SPLIT 16

__device__ __forceinline__ float gelu_exact(float v) {
    return 0.5f * v * (1.0f + erff(v * 0.70710678118654752f));
}

// ---------------------------------------------------------------------------
// Generic tiled GEMM: C[m*ldc+n] = epi( sum_k A[m*K+k] * W[n*K+k] + bias[n] )
// epi: if act==1 -> gelu; if scale -> *= scale[m]; if res -> += res[m*ldc+n]
// M % 64 == 0, N % 64 == 0, K % 32 == 0.
// LDS rows padded to 68 floats (272B, 16B-multiple) -> ds_read_b128 frags.
// ---------------------------------------------------------------------------
__global__ __launch_bounds__(256) void gemm_kernel(
    const float* __restrict__ A, const float* __restrict__ W,
    const float* __restrict__ bias,
    const float* __restrict__ res,
    const float* __restrict__ scale,
    float* __restrict__ C,
    int M, int N, int K, int ldc, int act)
{
    __shared__ float As[32][68];   // [k][m]
    __shared__ float Ws[32][68];   // [k][n]
    const int tid = threadIdx.x;
    const int tx = tid % 16, ty = tid / 16;
    const int m0 = blockIdx.x * 64, n0 = blockIdx.y * 64;

    float acc[4][4] = {};

    for (int k0 = 0; k0 < K; k0 += 32) {
        // stage: 64 rows x 32 k, float4 global loads, transposed scalar LDS writes
        #pragma unroll
        for (int it = 0; it < 2; ++it) {
            int idx = tid + it * 256;
            int r = idx / 8, c4 = (idx % 8) * 4;
            float4 av = *(const float4*)&A[(size_t)(m0 + r) * K + k0 + c4];
            float4 wv = *(const float4*)&W[(size_t)(n0 + r) * K + k0 + c4];
            As[c4 + 0][r] = av.x; As[c4 + 1][r] = av.y;
            As[c4 + 2][r] = av.z; As[c4 + 3][r] = av.w;
            Ws[c4 + 0][r] = wv.x; Ws[c4 + 1][r] = wv.y;
            Ws[c4 + 2][r] = wv.z; Ws[c4 + 3][r] = wv.w;
        }
        __syncthreads();
        #pragma unroll
        for (int kk = 0; kk < 32; ++kk) {
            float4 af = *(const float4*)&As[kk][ty * 4];
            float4 wf = *(const float4*)&Ws[kk][tx * 4];
            float a[4] = {af.x, af.y, af.z, af.w};
            float w[4] = {wf.x, wf.y, wf.z, wf.w};
            #pragma unroll
            for (int i = 0; i < 4; ++i)
                #pragma unroll
                for (int j = 0; j < 4; ++j)
                    acc[i][j] = fmaf(a[i], w[j], acc[i][j]);
        }
        __syncthreads();
    }

    float4 bv = *(const float4*)&bias[n0 + tx * 4];
    float bvv[4] = {bv.x, bv.y, bv.z, bv.w};
    #pragma unroll
    for (int i = 0; i < 4; ++i) {
        int m = m0 + ty * 4 + i;
        float sc = (scale != nullptr) ? scale[m] : 1.0f;
        float o[4];
        #pragma unroll
        for (int j = 0; j < 4; ++j) {
            float v = acc[i][j] + bvv[j];
            if (act == 1) v = gelu_exact(v);
            o[j] = v * sc;
        }
        size_t off = (size_t)m * ldc + n0 + tx * 4;
        if (res != nullptr) {
            float4 rv = *(const float4*)&res[off];
            o[0] += rv.x; o[1] += rv.y; o[2] += rv.z; o[3] += rv.w;
        }
        float4 ov = {o[0], o[1], o[2], o[3]};
        *(float4*)&C[off] = ov;
    }
}

// ---------------------------------------------------------------------------
// LayerNorm over rows of 128 (in-place), eps = 1e-5. Shuffle reduction.
// ---------------------------------------------------------------------------
__global__ __launch_bounds__(128) void ln_kernel(
    float* __restrict__ x, const float* __restrict__ g, const float* __restrict__ b)
{
    const int row = blockIdx.x, tid = threadIdx.x;
    __shared__ float cross[2][2];
    float v = x[(size_t)row * 128 + tid];
    float s = v, q = v * v;
    #pragma unroll
    for (int o = 32; o > 0; o >>= 1) {
        s += __shfl_xor(s, o, 64);
        q += __shfl_xor(q, o, 64);
    }
    int wid = tid >> 6;
    if ((tid & 63) == 0) { cross[0][wid] = s; cross[1][wid] = q; }
    __syncthreads();
    float mu  = (cross[0][0] + cross[0][1]) * (1.0f / 128.0f);
    float ex2 = (cross[1][0] + cross[1][1]) * (1.0f / 128.0f);
    float var = ex2 - mu * mu;
    x[(size_t)row * 128 + tid] = (v - mu) * rsqrtf(var + 1e-5f) * g[tid] + b[tid];
}

// ---------------------------------------------------------------------------
// Cosine normalize rows of 128: out = in / max(||in||, 1e-8)
// ---------------------------------------------------------------------------
__global__ __launch_bounds__(128) void cosnorm_kernel(
    const float* __restrict__ in, float* __restrict__ out)
{
    const int row = blockIdx.x, tid = threadIdx.x;
    __shared__ float cross[2];
    float v = in[(size_t)row * 128 + tid];
    float q = v * v;
    #pragma unroll
    for (int o = 32; o > 0; o >>= 1) q += __shfl_xor(q, o, 64);
    if ((tid & 63) == 0) cross[tid >> 6] = q;
    __syncthreads();
    float n = fmaxf(sqrtf(cross[0] + cross[1]), 1e-8f);
    out[(size_t)row * 128 + tid] = v / n;
}

// ---------------------------------------------------------------------------
// Windowed causal attention. qkv: (NTOK, 384) = [q|k|v], heads of 16.
// ---------------------------------------------------------------------------
__global__ __launch_bounds__(64) void win_attn_kernel(
    const float* __restrict__ qkv, float* __restrict__ out)
{
    const int w = blockIdx.x, h = blockIdx.y, l = threadIdx.x;
    __shared__ float Ks[64][16];
    __shared__ float Vs[64][16];
    const float* base = qkv + (size_t)(w * 64 + l) * 384 + h * 16;
    #pragma unroll
    for (int c4 = 0; c4 < 16; c4 += 4) {
        *(float4*)&Ks[l][c4] = *(const float4*)(base + 128 + c4);
        *(float4*)&Vs[l][c4] = *(const float4*)(base + 256 + c4);
    }
    float q[16];
    #pragma unroll
    for (int c = 0; c < 16; ++c) q[c] = base[c];
    __syncthreads();

    float m = -1e30f, ssum = 0.0f;
    float o[16] = {};
    for (int j = 0; j <= l; ++j) {
        float s = 0.0f;
        #pragma unroll
        for (int c = 0; c < 16; ++c) s = fmaf(q[c], Ks[j][c], s);
        s *= 0.25f;
        float mnew = fmaxf(m, s);
        float corr = expf(m - mnew);
        float p = expf(s - mnew);
        ssum = ssum * corr + p;
        #pragma unroll
        for (int c = 0; c < 16; ++c) o[c] = o[c] * corr + p * Vs[j][c];
        m = mnew;
    }
    float inv = 1.0f / ssum;
    float* op = out + (size_t)(w * 64 + l) * 128 + h * 16;
    #pragma unroll
    for (int c = 0; c < 16; ++c) op[c] = o[c] * inv;
}

// ---------------------------------------------------------------------------
// Split-K A^T B per batch: part[(b*ATB_SPLIT+chunk)*16384 + d*128 + e]
//   = sum_{j in chunk} sn[b][j][d] * tn[b][j][e]
// grid (2,2,8*ATB_SPLIT), 256 threads, 64x64 tile, 128 j-rows per chunk.
// ---------------------------------------------------------------------------
__global__ __launch_bounds__(256) void atb_split_kernel(
    const float* __restrict__ sn, const float* __restrict__ tn,
    float* __restrict__ part)
{
    const int b = blockIdx.z / ATB_SPLIT;
    const int chunk = blockIdx.z % ATB_SPLIT;
    const int d0 = blockIdx.x * 64, e0 = blockIdx.y * 64;
    __shared__ float Ss[32][68];
    __shared__ float Ts[32][68];
    const int tid = threadIdx.x;
    const int tx = tid % 16, ty = tid / 16;
    const float* sb = sn + (size_t)b * SS * 128;
    const float* tb = tn + (size_t)b * SS * 128;
    const int jbase = chunk * (SS / ATB_SPLIT);   // 128 rows per chunk
    float acc[4][4] = {};
    for (int j0 = jbase; j0 < jbase + SS / ATB_SPLIT; j0 += 32) {
        #pragma unroll
        for (int it = 0; it < 2; ++it) {
            int idx = tid + it * 256;
            int r = idx / 16, c4 = (idx % 16) * 4;
            *(float4*)&Ss[r][c4] = *(const float4*)&sb[(size_t)(j0 + r) * 128 + d0 + c4];
            *(float4*)&Ts[r][c4] = *(const float4*)&tb[(size_t)(j0 + r) * 128 + e0 + c4];
        }
        __syncthreads();
        #pragma unroll
        for (int kk = 0; kk < 32; ++kk) {
            float4 af = *(const float4*)&Ss[kk][ty * 4];
            float4 wf = *(const float4*)&Ts[kk][tx * 4];
            float a[4] = {af.x, af.y, af.z, af.w};
            float w[4] = {wf.x, wf.y, wf.z, wf.w};
            #pragma unroll
            for (int i = 0; i < 4; ++i)
                #pragma unroll
                for (int j = 0; j < 4; ++j)
                    acc[i][j] = fmaf(a[i], w[j], acc[i][j]);
        }
        __syncthreads();
    }
    float* pp = part + (size_t)(b * ATB_SPLIT + chunk) * 16384;
    #pragma unroll
    for (int i = 0; i < 4; ++i) {
        float4 ov = {acc[i][0], acc[i][1], acc[i][2], acc[i][3]};
        *(float4*)&pp[(size_t)(d0 + ty * 4 + i) * 128 + e0 + tx * 4] = ov;
    }
}

// Mb[b*16384+pos] = sum_chunk part[(b*ATB_SPLIT+chunk)*16384 + pos]
__global__ __launch_bounds__(256) void atb_reduce_kernel(
    const float* __restrict__ part, float* __restrict__ Mb)
{
    int i = blockIdx.x * 256 + threadIdx.x;      // 0..131071
    int b = i / 16384, pos = i % 16384;
    const float* pp = part + (size_t)b * ATB_SPLIT * 16384 + pos;
    float s = 0.0f;
    #pragma unroll
    for (int c = 0; c < ATB_SPLIT; ++c) s += pp[(size_t)c * 16384];
    Mb[i] = s;
}

// ---------------------------------------------------------------------------
// sim[row] = (1/S) * sn_row^T M_b tn_row.  16 rows per block, 256 threads.
// ---------------------------------------------------------------------------
__global__ __launch_bounds__(256) void sim_kernel(
    const float* __restrict__ sn, const float* __restrict__ tn,
    const float* __restrict__ Mb, float* __restrict__ sim)
{
    const int row0 = blockIdx.x * 16;
    const int b = row0 / SS;
    __shared__ float sn_s[16][128];
    __shared__ float tn_s[16][128];
    __shared__ float red[16][128];
    const int tid = threadIdx.x;
    for (int i4 = tid; i4 < 512; i4 += 256) {
        int r = i4 / 32, c4 = (i4 % 32) * 4;
        *(float4*)&sn_s[r][c4] = *(const float4*)&sn[(size_t)(row0 + r) * 128 + c4];
        *(float4*)&tn_s[r][c4] = *(const float4*)&tn[(size_t)(row0 + r) * 128 + c4];
    }
    __syncthreads();
    const int e = tid % 128, half = tid / 128;
    float acc[8] = {};
    const float* Mp = Mb + (size_t)b * 16384;
    for (int d = 0; d < 128; ++d) {
        float mv = Mp[(size_t)d * 128 + e];
        #pragma unroll
        for (int r = 0; r < 8; ++r) acc[r] = fmaf(sn_s[half * 8 + r][d], mv, acc[r]);
    }
    #pragma unroll
    for (int r = 0; r < 8; ++r) red[half * 8 + r][e] = acc[r] * tn_s[half * 8 + r][e];
    __syncthreads();
    if (tid < 16) {
        float s = 0.0f;
        for (int e2 = 0; e2 < 128; ++e2) s += red[tid][e2];
        sim[row0 + tid] = s * (1.0f / (float)SS);
    }
}

// ---------------------------------------------------------------------------
// Interaction attention (seq over batch dim, len=8, heads=8, hd=16, no mask).
// ---------------------------------------------------------------------------
__global__ __launch_bounds__(64) void inter_attn_kernel(
    const float* __restrict__ qkvi, float* __restrict__ AO)
{
    const int s = blockIdx.x, tid = threadIdx.x;
    __shared__ float Q[8][128];
    __shared__ float Km[8][128];
    __shared__ float Vm[8][128];
    __shared__ float P[8][8][8];
    for (int i4 = tid; i4 < 768; i4 += 64) {
        int mat = i4 / 256, rem = i4 % 256;
        int i = rem / 32, c4 = (rem % 32) * 4;
        float4 v = *(const float4*)(qkvi + (size_t)(i * SS + s) * 384 + mat * 128 + c4);
        float* dst = (mat == 0) ? &Q[i][c4] : (mat == 1) ? &Km[i][c4] : &Vm[i][c4];
        *(float4*)dst = v;
    }
    __syncthreads();
    for (int idx = tid; idx < 512; idx += 64) {
        int h = idx >> 6, i = (idx >> 3) & 7, j = idx & 7;
        float sum = 0.0f;
        #pragma unroll
        for (int c = 0; c < 16; ++c) sum = fmaf(Q[i][h * 16 + c], Km[j][h * 16 + c], sum);
        P[h][i][j] = sum * 0.25f;
    }
    __syncthreads();
    {
        int h = tid >> 3, i = tid & 7;
        float m = -1e30f;
        #pragma unroll
        for (int j = 0; j < 8; ++j) m = fmaxf(m, P[h][i][j]);
        float pj[8], ssum = 0.0f;
        #pragma unroll
        for (int j = 0; j < 8; ++j) { pj[j] = expf(P[h][i][j] - m); ssum += pj[j]; }
        float inv = 1.0f / ssum;
        #pragma unroll
        for (int j = 0; j < 8; ++j) P[h][i][j] = pj[j] * inv;
    }
    __syncthreads();
    for (int o = tid; o < 1024; o += 64) {
        int i = o >> 7, c = o & 127, h = c >> 4;
        float sum = 0.0f;
        #pragma unroll
        for (int j = 0; j < 8; ++j) sum = fmaf(P[h][i][j], Vm[j][c], sum);
        AO[(size_t)(i * SS + s) * 128 + c] = sum;
    }
}

// ---------------------------------------------------------------------------
extern "C" void kernel_launch(void* const* d_in, const int* in_sizes, int n_in,
                              void* d_out, int out_size, void* d_ws, size_t ws_size,
                              hipStream_t stream)
{
    const float* x        = (const float*)d_in[0];
    const float* spatial  = (const float*)d_in[1];
    const float* temporal = (const float*)d_in[2];
    const float* lw_in_w  = (const float*)d_in[3];
    const float* lw_in_b  = (const float*)d_in[4];
    const float* lw_out_w = (const float*)d_in[5];
    const float* lw_out_b = (const float*)d_in[6];
    const float* spat_w   = (const float*)d_in[7];
    const float* spat_b   = (const float*)d_in[8];
    const float* temp_w   = (const float*)d_in[9];
    const float* temp_b   = (const float*)d_in[10];
    const float* int_in_w = (const float*)d_in[11];
    const float* int_in_b = (const float*)d_in[12];
    const float* int_out_w= (const float*)d_in[13];
    const float* int_out_b= (const float*)d_in[14];
    const float* ffn_w1   = (const float*)d_in[15];
    const float* ffn_b1   = (const float*)d_in[16];
    const float* ffn_w2   = (const float*)d_in[17];
    const float* ffn_b2   = (const float*)d_in[18];
    const float* ln1_g    = (const float*)d_in[19];
    const float* ln1_b    = (const float*)d_in[20];
    const float* ln2_g    = (const float*)d_in[21];
    const float* ln2_b    = (const float*)d_in[22];
    float* out = (float*)d_out;

    float* ws = (float*)d_ws;
    float* qkvbuf = ws;                     // 6,291,456 floats
    float* attnbuf = qkvbuf + 6291456;      // 2,097,152
    float* x1buf  = attnbuf + 2097152;      // 2,097,152
    float* hbuf   = x1buf + 2097152;        // 8,388,608
    float* x2buf  = hbuf + 8388608;         // 2,097,152
    float* snbuf  = x2buf + 2097152;        // 2,097,152
    float* tnbuf  = snbuf + 2097152;        // 2,097,152
    float* Mbuf   = tnbuf + 2097152;        // 131,072
    float* simbuf = Mbuf + 131072;          // 16,384
    float* sebuf = x1buf;                   // alias (x1 dead after FFN2)
    float* tebuf = hbuf;                    // alias (h dead after FFN2)
    float* partbuf = qkvbuf;                // alias (qkv dead between steps 3..13)

    // --- 1. window QKV ---
    gemm_kernel<<<dim3(NTOK / 64, 6), 256, 0, stream>>>(
        x, lw_in_w, lw_in_b, nullptr, nullptr, qkvbuf, NTOK, 384, 128, 384, 0);
    // --- 2. windowed causal attention ---
    win_attn_kernel<<<dim3(256, 8), 64, 0, stream>>>(qkvbuf, attnbuf);
    // --- 3. out proj + residual(x) ---
    gemm_kernel<<<dim3(NTOK / 64, 2), 256, 0, stream>>>(
        attnbuf, lw_out_w, lw_out_b, x, nullptr, x1buf, NTOK, 128, 128, 128, 0);
    // --- 4. LN1 ---
    ln_kernel<<<NTOK, 128, 0, stream>>>(x1buf, ln1_g, ln1_b);
    // --- 5. FFN1 + GELU ---
    gemm_kernel<<<dim3(NTOK / 64, 8), 256, 0, stream>>>(
        x1buf, ffn_w1, ffn_b1, nullptr, nullptr, hbuf, NTOK, 512, 128, 512, 1);
    // --- 6. FFN2 + residual(x1) ---
    gemm_kernel<<<dim3(NTOK / 64, 2), 256, 0, stream>>>(
        hbuf, ffn_w2, ffn_b2, x1buf, nullptr, x2buf, NTOK, 128, 512, 128, 0);
    // --- 7. LN2 ---
    ln_kernel<<<NTOK, 128, 0, stream>>>(x2buf, ln2_g, ln2_b);
    // --- 8/9. se, te projections ---
    gemm_kernel<<<dim3(NTOK / 64, 2), 256, 0, stream>>>(
        spatial, spat_w, spat_b, nullptr, nullptr, sebuf, NTOK, 128, 128, 128, 0);
    gemm_kernel<<<dim3(NTOK / 64, 2), 256, 0, stream>>>(
        temporal, temp_w, temp_b, nullptr, nullptr, tebuf, NTOK, 128, 128, 128, 0);
    // --- 10. cosine norms ---
    cosnorm_kernel<<<NTOK, 128, 0, stream>>>(sebuf, snbuf);
    cosnorm_kernel<<<NTOK, 128, 0, stream>>>(tebuf, tnbuf);
    // --- 11. M_b = sn^T tn per batch (split-K + reduce, partials in qkvbuf) ---
    atb_split_kernel<<<dim3(2, 2, 8 * ATB_SPLIT), 256, 0, stream>>>(snbuf, tnbuf, partbuf);
    atb_reduce_kernel<<<512, 256, 0, stream>>>(partbuf, Mbuf);
    // --- 12. sim ---
    sim_kernel<<<NTOK / 16, 256, 0, stream>>>(snbuf, tnbuf, Mbuf, simbuf);
    // --- 13. interaction QKV: q from se, k/v from te ---
    gemm_kernel<<<dim3(NTOK / 64, 2), 256, 0, stream>>>(
        sebuf, int_in_w, int_in_b, nullptr, nullptr, qkvbuf, NTOK, 128, 128, 384, 0);
    gemm_kernel<<<dim3(NTOK / 64, 4), 256, 0, stream>>>(
        tebuf, int_in_w + 128 * 128, int_in_b + 128, nullptr, nullptr,
        qkvbuf + 128, NTOK, 256, 128, 384, 0);
    // --- 14. interaction attention ---
    inter_attn_kernel<<<SS, 64, 0, stream>>>(qkvbuf, attnbuf);
    // --- 15. out proj * sim + x2 -> d_out ---
    gemm_kernel<<<dim3(NTOK / 64, 2), 256, 0, stream>>>(
        attnbuf, int_out_w, int_out_b, x2buf, simbuf, out, NTOK, 128, 128, 128, 0);
}